// Round 1
// baseline (252.645 us; speedup 1.0000x reference)
//
#include <hip/hip_runtime.h>
#include <cstdint>
#include <cstddef>

// VQ-VAE quantization forward, MI355X/gfx950 — bf16 split-precision MFMA version.
// dot(x, e_norm) = xh*eh + xh*el + xl*eh  (3x mfma_f32_16x16x32_bf16, fp32 accum)
//
// v2: full-K per wave (in-register argmin, no LDS combine), double-buffered
// 32KB chunk staging with counted vmcnt + raw barriers, batched inline-asm
// ds_read_b128 with counted lgkmcnt (8-phase-template discipline).

typedef __attribute__((ext_vector_type(8))) short short8;
typedef __attribute__((ext_vector_type(4))) float f32x4;

namespace {
constexpr int kNT = 25600;           // N*T rows
constexpr int kD  = 1024;            // feature dim
constexpr int kM  = 256;             // codebook size
constexpr size_t kQElems = (size_t)kNT * kD;

// ws layout (float units). Codebook images: 32 chunks x [n=256][k=32] bf16,
// 16B sub-blocks swizzled: element idx = c*8192 + n*32 + (g ^ ((n>>1)&3))*8 + (k&7)
constexpr int WS_IMG_H = 0;                    // 262144 ushort = 131072 floats
constexpr int WS_IMG_L = 131072;               // 262144 ushort
constexpr int WS_E2N   = 262144;               // ||e_norm||^2 (256)
constexpr int WS_SCL   = WS_E2N + kM;          // ||e_raw|| + 1e-4 (256)
constexpr int WS_E2R   = WS_SCL + kM;          // ||e_raw||^2 (256)
constexpr int WS_COM   = WS_E2R + kM;          // commitment accumulator
constexpr int WS_HIST  = WS_COM + 4;           // histogram 256 ints
constexpr int WS_ZERO_BYTES = (WS_HIST + kM - WS_COM) * 4;
}

typedef __attribute__((address_space(3))) unsigned int        lds_u32;
typedef const __attribute__((address_space(1))) unsigned int  glb_u32;
typedef const __attribute__((address_space(3))) char          lds_chc;

__device__ __forceinline__ void gl2lds16(const void* g, void* l) {
  __builtin_amdgcn_global_load_lds((glb_u32*)g, (lds_u32*)l, 16, 0, 0);
}

// inline-asm LDS read: compile-time offset immediate, no compiler-inserted
// waitcnt (we count lgkmcnt manually per rule #18 + sched_barrier).
template <int OFF>
__device__ __forceinline__ short8 ldsr(lds_chc* p) {
  short8 r;
  asm volatile("ds_read_b128 %0, %1 offset:%c2" : "=v"(r) : "v"(p), "i"(OFF));
  return r;
}

// ---------------- kernel 1: normalize codebook -> swizzled bf16 hi/lo images + stats ----
__global__ __launch_bounds__(256) void vq_normalize(const float* __restrict__ emb,
                                                    float* __restrict__ ws) {
  const int m = blockIdx.x;
  const int t = threadIdx.x;
  const float4 v = reinterpret_cast<const float4*>(emb + (size_t)m * kD)[t];
  float s = v.x * v.x + v.y * v.y + v.z * v.z + v.w * v.w;
#pragma unroll
  for (int mask = 32; mask >= 1; mask >>= 1) s += __shfl_xor(s, mask);
  __shared__ float red[4];
  if ((t & 63) == 0) red[t >> 6] = s;
  __syncthreads();
  const float tot = red[0] + red[1] + red[2] + red[3];
  const float sc  = sqrtf(tot) + 1e-4f;
  const float inv = 1.0f / sc;
  const float4 nv = make_float4(v.x * inv, v.y * inv, v.z * inv, v.w * inv);

  float s2 = nv.x * nv.x + nv.y * nv.y + nv.z * nv.z + nv.w * nv.w;
#pragma unroll
  for (int mask = 32; mask >= 1; mask >>= 1) s2 += __shfl_xor(s2, mask);
  __syncthreads();
  if ((t & 63) == 0) red[t >> 6] = s2;
  __syncthreads();
  if (t == 0) {
    ws[WS_E2N + m] = red[0] + red[1] + red[2] + red[3];
    ws[WS_SCL + m] = sc;
    ws[WS_E2R + m] = tot;
  }

  // hi/lo truncation split, packed to the swizzled image
  unsigned short* imgh = (unsigned short*)(ws + WS_IMG_H);
  unsigned short* imgl = (unsigned short*)(ws + WS_IMG_L);
  const int c  = t >> 3;              // k-chunk (k = 4t..4t+3)
  const int g  = (t >> 1) & 3;        // 8-elem group within chunk
  const int sq = g ^ ((m >> 1) & 3);  // bank swizzle
  const int base = c * 8192 + m * 32 + sq * 8 + 4 * (t & 1);
  ushort4 hq, lq;
#pragma unroll
  for (int j = 0; j < 4; ++j) {
    const float fv = (&nv.x)[j];
    const unsigned int b = __float_as_uint(fv);
    const unsigned short hi = (unsigned short)(b >> 16);
    const float lof = fv - __uint_as_float(b & 0xFFFF0000u);
    const unsigned short lo = (unsigned short)(__float_as_uint(lof) >> 16);
    (&hq.x)[j] = hi; (&lq.x)[j] = lo;
  }
  *(ushort4*)(imgh + base) = hq;
  *(ushort4*)(imgl + base) = lq;
}

// ---------------- kernel 2: MFMA distances + argmin + gather + stats ----------------
// 400 blocks x 256 threads (4 waves). Wave w: rows [blk*64 + w*16, +16),
// all 256 codes, full K=1024. Per K-chunk of 32: block stages shared 32KB
// hi+lo codebook chunk into buf[kc&1] while computing on buf[kc^1].

// read one 4-ct batch (hi + lo fragments) from buffer BSEL
#define RD8(BSEL, G, H0, H1, H2, H3, L0, L1, L2, L3)                           \
  H0 = ldsr<(BSEL) * 32768 + ((G) * 4 + 0) * 1024>(lbase);                     \
  H1 = ldsr<(BSEL) * 32768 + ((G) * 4 + 1) * 1024>(lbase);                     \
  H2 = ldsr<(BSEL) * 32768 + ((G) * 4 + 2) * 1024>(lbase);                     \
  H3 = ldsr<(BSEL) * 32768 + ((G) * 4 + 3) * 1024>(lbase);                     \
  L0 = ldsr<(BSEL) * 32768 + 16384 + ((G) * 4 + 0) * 1024>(lbase);             \
  L1 = ldsr<(BSEL) * 32768 + 16384 + ((G) * 4 + 1) * 1024>(lbase);             \
  L2 = ldsr<(BSEL) * 32768 + 16384 + ((G) * 4 + 2) * 1024>(lbase);             \
  L3 = ldsr<(BSEL) * 32768 + 16384 + ((G) * 4 + 3) * 1024>(lbase);

// 12 MFMAs for one 4-ct batch (3-term split), round-robin for dep distance 4
#define MM12(G, H0, H1, H2, H3, L0, L1, L2, L3)                                              \
  acc[(G) * 4 + 0] = __builtin_amdgcn_mfma_f32_16x16x32_bf16(ah, H0, acc[(G) * 4 + 0], 0, 0, 0); \
  acc[(G) * 4 + 1] = __builtin_amdgcn_mfma_f32_16x16x32_bf16(ah, H1, acc[(G) * 4 + 1], 0, 0, 0); \
  acc[(G) * 4 + 2] = __builtin_amdgcn_mfma_f32_16x16x32_bf16(ah, H2, acc[(G) * 4 + 2], 0, 0, 0); \
  acc[(G) * 4 + 3] = __builtin_amdgcn_mfma_f32_16x16x32_bf16(ah, H3, acc[(G) * 4 + 3], 0, 0, 0); \
  acc[(G) * 4 + 0] = __builtin_amdgcn_mfma_f32_16x16x32_bf16(ah, L0, acc[(G) * 4 + 0], 0, 0, 0); \
  acc[(G) * 4 + 1] = __builtin_amdgcn_mfma_f32_16x16x32_bf16(ah, L1, acc[(G) * 4 + 1], 0, 0, 0); \
  acc[(G) * 4 + 2] = __builtin_amdgcn_mfma_f32_16x16x32_bf16(ah, L2, acc[(G) * 4 + 2], 0, 0, 0); \
  acc[(G) * 4 + 3] = __builtin_amdgcn_mfma_f32_16x16x32_bf16(ah, L3, acc[(G) * 4 + 3], 0, 0, 0); \
  acc[(G) * 4 + 0] = __builtin_amdgcn_mfma_f32_16x16x32_bf16(al, H0, acc[(G) * 4 + 0], 0, 0, 0); \
  acc[(G) * 4 + 1] = __builtin_amdgcn_mfma_f32_16x16x32_bf16(al, H1, acc[(G) * 4 + 1], 0, 0, 0); \
  acc[(G) * 4 + 2] = __builtin_amdgcn_mfma_f32_16x16x32_bf16(al, H2, acc[(G) * 4 + 2], 0, 0, 0); \
  acc[(G) * 4 + 3] = __builtin_amdgcn_mfma_f32_16x16x32_bf16(al, H3, acc[(G) * 4 + 3], 0, 0, 0);

// one K-chunk iteration. BSEL = kc&1 (compile-time). XC = x regs for this kc
// (loaded last iter), XN = x regs being loaded for kc+1.
// vmcnt(10) = this iter's 2 x-loads + 8 stage loads stay in flight; everything
// issued before this iteration is forced complete.
#define VQ_ITER(KC, BSEL, XC0, XC1, XN0, XN1)                                  \
  {                                                                            \
    const int kcn_ = ((KC) < 31) ? (KC) + 1 : 31;                              \
    const float* xp_ = xrow + kcn_ * 32;                                       \
    XN0 = *(const float4*)xp_;                                                 \
    XN1 = *(const float4*)(xp_ + 4);                                           \
    {                                                                          \
      const unsigned short* sg_ = simg + ((size_t)kcn_ << 13) + soff;          \
      char* dg_ = &buf[(BSEL) ^ 1][0] + ldst;                                  \
      _Pragma("unroll")                                                        \
      for (int it_ = 0; it_ < 8; ++it_)                                        \
        gl2lds16(sg_ + it_ * 512, dg_ + it_ * 1024);                           \
    }                                                                          \
    asm volatile("s_waitcnt vmcnt(10)" ::: "memory");                          \
    __builtin_amdgcn_s_barrier();                                              \
    asm volatile("" ::: "memory");                                             \
    short8 ha0_, ha1_, ha2_, ha3_, la0_, la1_, la2_, la3_;                     \
    short8 hb0_, hb1_, hb2_, hb3_, lb0_, lb1_, lb2_, lb3_;                     \
    RD8((BSEL), 0, ha0_, ha1_, ha2_, ha3_, la0_, la1_, la2_, la3_)             \
    RD8((BSEL), 1, hb0_, hb1_, hb2_, hb3_, lb0_, lb1_, lb2_, lb3_)             \
    short8 ah, al;                                                             \
    {                                                                          \
      union { short8 v; unsigned short u[8]; } H_, L_;                         \
      const float fx_[8] = {XC0.x, XC0.y, XC0.z, XC0.w,                        \
                            XC1.x, XC1.y, XC1.z, XC1.w};                       \
      _Pragma("unroll")                                                        \
      for (int jj_ = 0; jj_ < 8; ++jj_) {                                      \
        const float fv_ = fx_[jj_];                                            \
        const unsigned int b_ = __float_as_uint(fv_);                          \
        H_.u[jj_] = (unsigned short)(b_ >> 16);                                \
        const float lo_ = fv_ - __uint_as_float(b_ & 0xFFFF0000u);             \
        L_.u[jj_] = (unsigned short)(__float_as_uint(lo_) >> 16);              \
        x2 += fv_ * fv_;                                                       \
      }                                                                        \
      ah = H_.v; al = L_.v;                                                    \
    }                                                                          \
    asm volatile("s_waitcnt lgkmcnt(8)" ::: "memory");                         \
    __builtin_amdgcn_sched_barrier(0);                                         \
    MM12(0, ha0_, ha1_, ha2_, ha3_, la0_, la1_, la2_, la3_)                    \
    RD8((BSEL), 2, ha0_, ha1_, ha2_, ha3_, la0_, la1_, la2_, la3_)             \
    asm volatile("s_waitcnt lgkmcnt(8)" ::: "memory");                         \
    __builtin_amdgcn_sched_barrier(0);                                         \
    MM12(1, hb0_, hb1_, hb2_, hb3_, lb0_, lb1_, lb2_, lb3_)                    \
    RD8((BSEL), 3, hb0_, hb1_, hb2_, hb3_, lb0_, lb1_, lb2_, lb3_)             \
    asm volatile("s_waitcnt lgkmcnt(8)" ::: "memory");                         \
    __builtin_amdgcn_sched_barrier(0);                                         \
    MM12(2, ha0_, ha1_, ha2_, ha3_, la0_, la1_, la2_, la3_)                    \
    asm volatile("s_waitcnt lgkmcnt(0)" ::: "memory");                         \
    __builtin_amdgcn_sched_barrier(0);                                         \
    MM12(3, hb0_, hb1_, hb2_, hb3_, lb0_, lb1_, lb2_, lb3_)                    \
    asm volatile("" ::: "memory");                                             \
    __builtin_amdgcn_s_barrier();                                              \
    asm volatile("" ::: "memory");                                             \
  }

__global__ __launch_bounds__(256, 2) void vq_main(const float* __restrict__ x,
                                                  const float* __restrict__ emb,
                                                  const float* __restrict__ wsc,
                                                  float* __restrict__ out,
                                                  float* __restrict__ commit_sum,
                                                  int* __restrict__ hist) {
  __shared__ char buf[2][32768];   // per buffer: [hi 16KB][lo 16KB] of one k-chunk

  const int t   = threadIdx.x;
  const int l   = t & 63;
  const int w   = t >> 6;
  const int r0  = blockIdx.x * 64 + w * 16;    // wave's 16 rows
  const int nlo = l & 15;
  const int q   = l >> 4;                       // k-quad / lane-group
  const int sq  = q ^ ((l >> 1) & 3);           // image bank swizzle

  // staging: wave w copies quarter w of the 32KB [hi|lo] chunk (linear dest)
  const unsigned short* imgH = (const unsigned short*)(wsc + WS_IMG_H);
  const unsigned short* imgL = (const unsigned short*)(wsc + WS_IMG_L);
  const unsigned short* simg = (w & 2) ? imgL : imgH;
  const int soff = (w & 1) * 4096 + l * 8;      // elems within chunk image
  const int ldst = w * 8192;                    // bytes within buf[b]

  const float* xrow = x + (size_t)(r0 + nlo) * kD + q * 8;
  lds_chc* lbase = (lds_chc*)&buf[0][0] + nlo * 64 + sq * 16;

  f32x4 acc[16];
#pragma unroll
  for (int i = 0; i < 16; ++i) acc[i] = (f32x4)0.0f;
  float x2 = 0.0f;

  // prologue: x for kc=0 and stage chunk 0 -> buf[0]   (10 VMEM ops in flight)
  float4 xa0, xa1, xb0, xb1;
  xa0 = *(const float4*)xrow;
  xa1 = *(const float4*)(xrow + 4);
  {
    const unsigned short* sg = simg + soff;
    char* dg = &buf[0][0] + ldst;
#pragma unroll
    for (int it = 0; it < 8; ++it) gl2lds16(sg + it * 512, dg + it * 1024);
  }

#pragma unroll 1
  for (int kk = 0; kk < 32; kk += 2) {
    VQ_ITER(kk,     0, xa0, xa1, xb0, xb1)
    VQ_ITER(kk + 1, 1, xb0, xb1, xa0, xa1)
  }

  // ---- x2 row totals: lane holds partial for row nlo over k-quad q
  x2 += __shfl_xor(x2, 16);
  x2 += __shfl_xor(x2, 32);   // all lanes with same nlo now hold full ||x_row||^2

  // ---- in-register argmin over 256 codes.
  // acc[ct][rg] at lane l = dot(row (q*4+rg), code ct*16+nlo); dist = e2n - 2*dot.
  float bv[4] = {3.0e38f, 3.0e38f, 3.0e38f, 3.0e38f};
  int   bj[4] = {0, 0, 0, 0};
#pragma unroll
  for (int ct = 0; ct < 16; ++ct) {
    const int j = ct * 16 + nlo;
    const float e = wsc[WS_E2N + j];
#pragma unroll
    for (int rg = 0; rg < 4; ++rg) {
      const float v = e - 2.0f * acc[ct][rg];
      if (v < bv[rg] || (v == bv[rg] && j < bj[rg])) { bv[rg] = v; bj[rg] = j; }
    }
  }
#pragma unroll
  for (int mk = 1; mk <= 8; mk <<= 1) {   // butterfly within 16-lane col group
#pragma unroll
    for (int rg = 0; rg < 4; ++rg) {
      const float ov = __shfl_xor(bv[rg], mk);
      const int   oj = __shfl_xor(bj[rg], mk);
      if (ov < bv[rg] || (ov == bv[rg] && oj < bj[rg])) { bv[rg] = ov; bj[rg] = oj; }
    }
  }

  // ---- commitment + histogram (quad q owns rows q*4+rg)
  float clq = 0.0f;
#pragma unroll
  for (int rg = 0; rg < 4; ++rg) {
    const int j = bj[rg];
    const float xr2 = __shfl(x2, (q << 2) | rg);
    // ||x - e_raw||^2 = ||x||^2 + ||e_raw||^2 - (e2n - bv)*scl   [(e2n-bv) = 2*dot]
    clq += xr2 + wsc[WS_E2R + j] - (wsc[WS_E2N + j] - bv[rg]) * wsc[WS_SCL + j];
  }
  if (nlo == 0) {
#pragma unroll
    for (int rg = 0; rg < 4; ++rg) atomicAdd(&hist[bj[rg]], 1);
  }
  float cs = (nlo == 0) ? clq : 0.0f;
  cs += __shfl_xor(cs, 16);
  cs += __shfl_xor(cs, 32);
  if (l == 0) atomicAdd(commit_sum, cs);   // one commit atomic per wave

  // ---- gather: quantized row = raw embedding[argmin], 16 rows per wave
  const float4* emb4 = (const float4*)emb;
  float4* out4 = (float4*)out;
#pragma unroll
  for (int r = 0; r < 16; ++r) {
    const int j = __shfl(bj[r & 3], (r >> 2) << 4);
    const float4* s = emb4 + (size_t)j * (kD / 4);
    float4* d = out4 + (size_t)(r0 + r) * (kD / 4);
#pragma unroll
    for (int c = 0; c < 4; ++c) d[c * 64 + l] = s[c * 64 + l];
  }
}

// ---------------- kernel 3: scalars ----------------
__global__ __launch_bounds__(256) void vq_final(const int* __restrict__ hist,
                                                const float* __restrict__ commit_sum,
                                                float* __restrict__ out) {
  const int t = threadIdx.x;
  const float p = (float)hist[t] * (1.0f / (float)kNT);
  float s = p * logf(p + 1e-10f);
#pragma unroll
  for (int mask = 32; mask >= 1; mask >>= 1) s += __shfl_xor(s, mask);
  __shared__ float red[4];
  if ((t & 63) == 0) red[t >> 6] = s;
  __syncthreads();
  if (t == 0) {
    const float ent = red[0] + red[1] + red[2] + red[3];
    out[kQElems]     = commit_sum[0] * (1.0f / (float)kQElems);
    out[kQElems + 1] = expf(-ent);
  }
}

extern "C" void kernel_launch(void* const* d_in, const int* in_sizes, int n_in,
                              void* d_out, int out_size, void* d_ws, size_t ws_size,
                              hipStream_t stream) {
  (void)in_sizes; (void)n_in; (void)out_size; (void)ws_size;
  const float* x   = (const float*)d_in[0];
  const float* emb = (const float*)d_in[1];
  float* out = (float*)d_out;
  float* ws  = (float*)d_ws;

  hipMemsetAsync((char*)d_ws + (size_t)WS_COM * 4, 0, WS_ZERO_BYTES, stream);
  hipLaunchKernelGGL(vq_normalize, dim3(kM), dim3(256), 0, stream, emb, ws);
  hipLaunchKernelGGL(vq_main, dim3(kNT / 64), dim3(256), 0, stream,
                     x, emb, ws, out, ws + WS_COM, (int*)(ws + WS_HIST));
  hipLaunchKernelGGL(vq_final, dim3(1), dim3(256), 0, stream,
                     (const int*)(ws + WS_HIST), ws + WS_COM, out);
}